// Round 3
// baseline (1687.264 us; speedup 1.0000x reference)
//
#include <hip/hip_runtime.h>
#include <hip/hip_bf16.h>
#include <stdint.h>

typedef unsigned int uint;

#define NNODES 100000
#define NEDGES 1600000
#define RCONST 400
#define NPB 8              // nodes per block in the fused layer kernel
#define NSEG (NNODES * 3)  // (node, bucket) segments

// ---------------- CSR build (bucket-partitioned) ----------------

__global__ __launch_bounds__(256) void deg3_kernel(const int* __restrict__ edges,
                                                   int* __restrict__ deg3, int E) {
    int e = blockIdx.x * 256 + threadIdx.x;
    if (e < E) {
        int rel = edges[e * 3 + 1];
        int dst = edges[e * 3 + 2];
        int bkt = (rel >= RCONST) + (rel >= 2 * RCONST);
        atomicAdd(&deg3[dst * 3 + bkt], 1);
    }
}

// Thread-coarsened exclusive scan over M elements, single block of 1024.
__global__ __launch_bounds__(1024) void scan_kernel(const int* __restrict__ deg,
                                                    int* __restrict__ rowstart, int M) {
    __shared__ int part[1024];
    int t = threadIdx.x;
    int chunk = (M + 1023) >> 10;
    int beg = t * chunk;
    int end = min(beg + chunk, M);

    // pass 1: per-thread sum
    int s = 0;
    for (int i = beg; i < end; ++i) s += deg[i];
    part[t] = s;
    __syncthreads();
    // block scan (inclusive, Hillis-Steele)
    for (int st = 1; st < 1024; st <<= 1) {
        int a = (t >= st) ? part[t - st] : 0;
        __syncthreads();
        part[t] += a;
        __syncthreads();
    }
    int run = (t == 0) ? 0 : part[t - 1];  // exclusive prefix of this chunk
    // pass 2: write exclusive scan
    for (int i = beg; i < end; ++i) {
        rowstart[i] = run;
        run += deg[i];
    }
    if (t == 1023) rowstart[M] = run;
}

__global__ __launch_bounds__(256) void fill3_kernel(const int* __restrict__ edges,
                                                    const int* __restrict__ rs3,
                                                    int* __restrict__ fill3,
                                                    int* __restrict__ elist, int E) {
    int e = blockIdx.x * 256 + threadIdx.x;
    if (e < E) {
        int src = edges[e * 3];
        int rel = edges[e * 3 + 1];
        int dst = edges[e * 3 + 2];
        int bkt = (rel >= RCONST) + (rel >= 2 * RCONST);
        int key = dst * 3 + bkt;
        int pos = rs3[key] + atomicAdd(&fill3[key], 1);
        elist[pos] = src;
    }
}

// ---------------- fused layer ----------------
// Per node d, bucket r:  S_r = sum x[src]  over segment (d,r)   [branch-free gather]
//   m = (sum_r W[r] @ S_r + sum_r cnt_r*b[r]) / max(cnt,1)
//   v = relu(m) + Ws @ x[d] + bs ;  out = layernorm(v)*g + be

__global__ __launch_bounds__(128) void layer_kernel(
    const float* __restrict__ x, const int* __restrict__ rs3,
    const int* __restrict__ elist,
    const float* __restrict__ W,  const float* __restrict__ b,
    const float* __restrict__ Ws, const float* __restrict__ bs,
    const float* __restrict__ g,  const float* __restrict__ be,
    float* __restrict__ y) {
    __shared__ float sS[NPB][3][128];
    __shared__ float sX[NPB][128];
    __shared__ float sCnt[NPB][3];
    __shared__ float sRed[2][NPB][2];

    int o = threadIdx.x;        // output channel 0..127
    int lane = o & 63, wid = o >> 6;
    int n0 = blockIdx.x * NPB;

    // ---- gather/aggregate phase: branch-free per-segment accumulation ----
    for (int n = 0; n < NPB; ++n) {
        int node = n0 + n;
        int base = node * 3;
        #pragma unroll
        for (int r = 0; r < 3; ++r) {
            int beg = rs3[base + r], end = rs3[base + r + 1];
            float a0 = 0.f, a1 = 0.f, a2 = 0.f, a3 = 0.f;
            int e = beg;
            for (; e + 4 <= end; e += 4) {
                int s0 = elist[e], s1 = elist[e + 1];
                int s2 = elist[e + 2], s3 = elist[e + 3];
                a0 += x[(size_t)s0 * 128 + o];
                a1 += x[(size_t)s1 * 128 + o];
                a2 += x[(size_t)s2 * 128 + o];
                a3 += x[(size_t)s3 * 128 + o];
            }
            for (; e < end; ++e) a0 += x[(size_t)elist[e] * 128 + o];
            sS[n][r][o] = (a0 + a1) + (a2 + a3);
            if (o == 0) sCnt[n][r] = (float)(end - beg);
        }
        sX[n][o] = x[(size_t)node * 128 + o];
    }
    __syncthreads();

    // ---- matvec phase: thread o computes output channel o for all NPB nodes ----
    float acc[NPB], accS[NPB];
    #pragma unroll
    for (int n = 0; n < NPB; ++n) { acc[n] = 0.f; accS[n] = 0.f; }

    for (int r = 0; r < 3; ++r) {
        const float4* Wrow = (const float4*)(W + ((size_t)(r * 128 + o)) * 128);
        #pragma unroll 8
        for (int kc = 0; kc < 32; ++kc) {
            float4 wq = Wrow[kc];
            int k = kc * 4;
            #pragma unroll
            for (int n = 0; n < NPB; ++n) {
                const float4 A = *(const float4*)&sS[n][r][k];
                acc[n] += wq.x * A.x + wq.y * A.y + wq.z * A.z + wq.w * A.w;
            }
        }
    }
    {
        const float4* Wrow = (const float4*)(Ws + (size_t)o * 128);
        #pragma unroll 8
        for (int kc = 0; kc < 32; ++kc) {
            float4 wq = Wrow[kc];
            int k = kc * 4;
            #pragma unroll
            for (int n = 0; n < NPB; ++n) {
                const float4 A = *(const float4*)&sX[n][k];
                accS[n] += wq.x * A.x + wq.y * A.y + wq.z * A.z + wq.w * A.w;
            }
        }
    }

    float bv0 = b[o], bv1 = b[128 + o], bv2 = b[256 + o];
    float bsv = bs[o], gv = g[o], bev = be[o];

    // ---- epilogue: bias, mean, relu, skip, layernorm ----
    #pragma unroll
    for (int n = 0; n < NPB; ++n) {
        float c0 = sCnt[n][0], c1 = sCnt[n][1], c2 = sCnt[n][2];
        float cnt = c0 + c1 + c2;
        float inv = 1.0f / fmaxf(cnt, 1.0f);
        float m = (acc[n] + c0 * bv0 + c1 * bv1 + c2 * bv2) * inv;
        float v = fmaxf(m, 0.0f) + accS[n] + bsv;

        float s1 = v, s2 = v * v;
        #pragma unroll
        for (int off = 32; off > 0; off >>= 1) {
            s1 += __shfl_down(s1, off, 64);
            s2 += __shfl_down(s2, off, 64);
        }
        if (lane == 0) { sRed[wid][n][0] = s1; sRed[wid][n][1] = s2; }
        __syncthreads();
        float S1 = sRed[0][n][0] + sRed[1][n][0];
        float S2 = sRed[0][n][1] + sRed[1][n][1];
        float mean = S1 * (1.0f / 128.0f);
        float var = S2 * (1.0f / 128.0f) - mean * mean;
        float rstd = rsqrtf(var + 1e-5f);
        float outv = (v - mean) * rstd * gv + bev;
        y[(size_t)(n0 + n) * 128 + o] = outv;
    }
}

// ---------------- launch ----------------

extern "C" void kernel_launch(void* const* d_in, const int* in_sizes, int n_in,
                              void* d_out, int out_size, void* d_ws, size_t ws_size,
                              hipStream_t stream) {
    (void)in_sizes; (void)n_in; (void)out_size; (void)ws_size;

    const int*   edges = (const int*)d_in[0];
    const float* xemb  = (const float*)d_in[1];
    const float* W1  = (const float*)d_in[2];
    const float* b1  = (const float*)d_in[3];
    const float* Ws1 = (const float*)d_in[4];
    const float* bs1 = (const float*)d_in[5];
    const float* g1  = (const float*)d_in[6];
    const float* be1 = (const float*)d_in[7];
    const float* W2  = (const float*)d_in[8];
    const float* b2  = (const float*)d_in[9];
    const float* Ws2 = (const float*)d_in[10];
    const float* bs2 = (const float*)d_in[11];
    const float* g2  = (const float*)d_in[12];
    const float* be2 = (const float*)d_in[13];

    char* ws = (char*)d_ws;
    auto take = [&](size_t bytes) {
        char* p = ws;
        ws += (bytes + 255) & ~(size_t)255;
        return p;
    };
    int*   deg3  = (int*)take((size_t)NSEG * 4);
    int*   rs3   = (int*)take((size_t)(NSEG + 1) * 4);
    int*   fill3 = (int*)take((size_t)NSEG * 4);
    int*   elist = (int*)take((size_t)NEDGES * 4);
    float* x1    = (float*)take((size_t)NNODES * 128 * 4);

    hipMemsetAsync(deg3, 0, (size_t)NSEG * 4, stream);
    hipMemsetAsync(fill3, 0, (size_t)NSEG * 4, stream);

    deg3_kernel<<<(NEDGES + 255) / 256, 256, 0, stream>>>(edges, deg3, NEDGES);
    scan_kernel<<<1, 1024, 0, stream>>>(deg3, rs3, NSEG);
    fill3_kernel<<<(NEDGES + 255) / 256, 256, 0, stream>>>(edges, rs3, fill3, elist, NEDGES);

    layer_kernel<<<NNODES / NPB, 128, 0, stream>>>(
        xemb, rs3, elist, W1, b1, Ws1, bs1, g1, be1, x1);
    layer_kernel<<<NNODES / NPB, 128, 0, stream>>>(
        x1, rs3, elist, W2, b2, Ws2, bs2, g2, be2, (float*)d_out);
}

// Round 4
// 658.490 us; speedup vs baseline: 2.5623x; 2.5623x over previous
//
#include <hip/hip_runtime.h>
#include <stdint.h>

typedef unsigned int uint;
typedef unsigned short ushort;

#define NNODES 100000
#define NPAD   100096          // NNODES rounded up to 128
#define NEDGES 1600000
#define RCONST 400
#define NSEG   300000
#define SCAN_NBLK 293          // ceil(NSEG/1024)

typedef __attribute__((ext_vector_type(8))) short short8;
typedef __attribute__((ext_vector_type(4))) float f32x4;

__device__ __forceinline__ float bflo(uint u){ union{uint i;float f;}c; c.i=u<<16; return c.f; }
__device__ __forceinline__ float bfhi(uint u){ union{uint i;float f;}c; c.i=u&0xFFFF0000u; return c.f; }
__device__ __forceinline__ ushort f2bf(float f){ union{uint i;float ff;}c; c.ff=f; uint u=c.i;
    return (ushort)((u + 0x7FFFu + ((u>>16)&1u))>>16); }
__device__ __forceinline__ uint pack2(float lo, float hi){
    return (uint)f2bf(lo) | ((uint)f2bf(hi)<<16); }

// ---------------- CSR build ----------------

__global__ __launch_bounds__(256) void deg3_kernel(const int* __restrict__ edges,
                                                   int* __restrict__ deg3) {
    int e = blockIdx.x * 256 + threadIdx.x;
    if (e < NEDGES) {
        int rel = edges[e * 3 + 1];
        int dst = edges[e * 3 + 2];
        int bkt = (rel >= RCONST) + (rel >= 2 * RCONST);
        atomicAdd(&deg3[dst * 3 + bkt], 1);
    }
}

__global__ __launch_bounds__(256) void scanA_kernel(const int* __restrict__ deg,
                                                    int* __restrict__ part) {
    __shared__ int sm[256];
    int t = threadIdx.x, b = blockIdx.x;
    int base = b * 1024 + t * 4;
    int s = 0;
    #pragma unroll
    for (int j = 0; j < 4; ++j) { int i = base + j; if (i < NSEG) s += deg[i]; }
    sm[t] = s; __syncthreads();
    for (int st = 1; st < 256; st <<= 1) {
        int a = (t >= st) ? sm[t - st] : 0;
        __syncthreads(); sm[t] += a; __syncthreads();
    }
    if (t == 255) part[b] = sm[255];
}

__global__ __launch_bounds__(512) void scanB_kernel(const int* __restrict__ part,
                                                    int* __restrict__ ppre,
                                                    int* __restrict__ rs3) {
    __shared__ int sm[512];
    int t = threadIdx.x;
    int v = (t < SCAN_NBLK) ? part[t] : 0;
    sm[t] = v; __syncthreads();
    for (int st = 1; st < 512; st <<= 1) {
        int a = (t >= st) ? sm[t - st] : 0;
        __syncthreads(); sm[t] += a; __syncthreads();
    }
    if (t < SCAN_NBLK) ppre[t] = sm[t] - v;
    if (t == 511) rs3[NSEG] = sm[511];
}

__global__ __launch_bounds__(256) void scanC_kernel(const int* __restrict__ deg,
                                                    const int* __restrict__ ppre,
                                                    int* __restrict__ rs3) {
    __shared__ int sm[256];
    int t = threadIdx.x, b = blockIdx.x;
    int base = b * 1024 + t * 4;
    int d0 = 0, d1 = 0, d2 = 0, d3 = 0;
    if (base + 3 < NSEG) {
        int4 q = *(const int4*)&deg[base];
        d0 = q.x; d1 = q.y; d2 = q.z; d3 = q.w;
    } else {
        if (base < NSEG)     d0 = deg[base];
        if (base + 1 < NSEG) d1 = deg[base + 1];
        if (base + 2 < NSEG) d2 = deg[base + 2];
        if (base + 3 < NSEG) d3 = deg[base + 3];
    }
    int tot = d0 + d1 + d2 + d3;
    sm[t] = tot; __syncthreads();
    for (int st = 1; st < 256; st <<= 1) {
        int a = (t >= st) ? sm[t - st] : 0;
        __syncthreads(); sm[t] += a; __syncthreads();
    }
    int run = ppre[b] + sm[t] - tot;
    if (base < NSEG)     { rs3[base]     = run; run += d0; }
    if (base + 1 < NSEG) { rs3[base + 1] = run; run += d1; }
    if (base + 2 < NSEG) { rs3[base + 2] = run; run += d2; }
    if (base + 3 < NSEG) { rs3[base + 3] = run; }
}

__global__ __launch_bounds__(256) void cnts_kernel(const int* __restrict__ deg3,
                                                   float4* __restrict__ cnts) {
    int n = blockIdx.x * 256 + threadIdx.x;
    if (n < NNODES) {
        float c0 = (float)deg3[n * 3], c1 = (float)deg3[n * 3 + 1], c2 = (float)deg3[n * 3 + 2];
        float tot = c0 + c1 + c2;
        float4 v; v.x = c0; v.y = c1; v.z = c2; v.w = 1.0f / fmaxf(tot, 1.0f);
        cnts[n] = v;
    }
}

__global__ __launch_bounds__(256) void fill3_kernel(const int* __restrict__ edges,
                                                    const int* __restrict__ rs3,
                                                    int* __restrict__ fill3,
                                                    int* __restrict__ elist) {
    int e = blockIdx.x * 256 + threadIdx.x;
    if (e < NEDGES) {
        int src = edges[e * 3];
        int rel = edges[e * 3 + 1];
        int dst = edges[e * 3 + 2];
        int bkt = (rel >= RCONST) + (rel >= 2 * RCONST);
        int key = dst * 3 + bkt;
        int pos = rs3[key] + atomicAdd(&fill3[key], 1);
        elist[pos] = src;
    }
}

// ---------------- conversions ----------------

__global__ __launch_bounds__(256) void convx_kernel(const float* __restrict__ x,
                                                    uint* __restrict__ xb) {
    size_t i = (size_t)blockIdx.x * 256 + threadIdx.x;   // pair index
    if (i < (size_t)NNODES * 64) {
        float2 f = *(const float2*)&x[i * 2];
        xb[i] = pack2(f.x, f.y);
    }
}

// Wb[n][k] bf16, k<384: W[k>>7][n][k&127]; k>=384: Ws[n][k-384]
__global__ __launch_bounds__(256) void wconv_kernel(const float* __restrict__ W,
                                                    const float* __restrict__ Ws,
                                                    uint* __restrict__ Wb) {
    int i = blockIdx.x * 256 + threadIdx.x;   // pair index, 128*256
    if (i < 128 * 256) {
        int n = i >> 8, kp = i & 255, k = kp * 2;
        float v0, v1;
        if (k < 384) {
            int r = k >> 7, kk = k & 127;
            const float* p = W + r * 16384 + n * 128 + kk;
            v0 = p[0]; v1 = p[1];
        } else {
            const float* p = Ws + n * 128 + (k - 384);
            v0 = p[0]; v1 = p[1];
        }
        Wb[i] = pack2(v0, v1);
    }
}

// ---------------- gather: one wave per (node,bucket) segment ----------------
// Writes A[node][r*128 .. +128] = inv * sum_{e in seg} x[src_e]   (bf16)

__global__ __launch_bounds__(256) void gather_kernel(
    const uint* __restrict__ xb,       // [NPAD][64] bf16-pairs
    const int* __restrict__ rs3,
    const int* __restrict__ elist,
    const float* __restrict__ cnts,    // [NPAD][4], .w = inv
    uint* __restrict__ Ab) {           // [NPAD][192] bf16-pairs
    int w = threadIdx.x >> 6, lane = threadIdx.x & 63;
    int seg = blockIdx.x * 4 + w;      // grid is exactly NSEG/4
    int node = seg / 3;
    int r = seg - node * 3;
    int beg = rs3[seg], end = rs3[seg + 1];
    float inv = cnts[node * 4 + 3];
    float a0l = 0, a0h = 0, a1l = 0, a1h = 0, a2l = 0, a2h = 0, a3l = 0, a3h = 0;
    int e = beg;
    for (; e + 4 <= end; e += 4) {
        int s0 = elist[e], s1 = elist[e + 1], s2 = elist[e + 2], s3 = elist[e + 3];
        uint u0 = xb[(size_t)s0 * 64 + lane];
        uint u1 = xb[(size_t)s1 * 64 + lane];
        uint u2 = xb[(size_t)s2 * 64 + lane];
        uint u3 = xb[(size_t)s3 * 64 + lane];
        a0l += bflo(u0); a0h += bfhi(u0);
        a1l += bflo(u1); a1h += bfhi(u1);
        a2l += bflo(u2); a2h += bfhi(u2);
        a3l += bflo(u3); a3h += bfhi(u3);
    }
    for (; e < end; ++e) {
        uint u = xb[(size_t)elist[e] * 64 + lane];
        a0l += bflo(u); a0h += bfhi(u);
    }
    float lo = ((a0l + a1l) + (a2l + a3l)) * inv;
    float hi = ((a0h + a1h) + (a2h + a3h)) * inv;
    Ab[(size_t)node * 192 + r * 64 + lane] = pack2(lo, hi);
}

// ---------------- MFMA GEMM + fused epilogue ----------------
// Tile: 128 nodes x 128 channels, K=512 (kc 0..2: scaled rel-sums from Ab;
// kc 3: x itself -> skip path, separate accumulator).
// Epilogue: m = accm + inv*(c.b); v = relu(m) + accq + bs; layernorm; store.

template<bool OUT_BF16>
__global__ __launch_bounds__(256, 2) void gemm_kernel(
    const ushort* __restrict__ Ab,     // [NPAD][384]
    const ushort* __restrict__ xb,     // [NPAD][128]
    const ushort* __restrict__ Wb,     // [128][512]
    const float* __restrict__ bia,     // [3][128]
    const float* __restrict__ bs,
    const float* __restrict__ g,
    const float* __restrict__ be,
    const float4* __restrict__ cnts,   // [NPAD] (c0,c1,c2,inv)
    void* __restrict__ out) {
    __shared__ char smem[128 * 136 * 2 * 2];   // A-stage + B-stage, reused as v-tile
    __shared__ float sMean[128], sRstd[128];
    ushort (*lA)[136] = (ushort(*)[136])smem;
    ushort (*lB)[136] = (ushort(*)[136])(smem + 128 * 136 * 2);
    float  (*vt)[132] = (float(*)[132])smem;

    int tid = threadIdx.x;
    int w = tid >> 6, lane = tid & 63;
    int wm = w >> 1, wn = w & 1;
    int quad = lane >> 4, l15 = lane & 15;
    int node0 = blockIdx.x * 128;

    f32x4 accm[4][4], accq[4][4];
    f32x4 zero = {0.f, 0.f, 0.f, 0.f};
    #pragma unroll
    for (int i = 0; i < 4; ++i)
        #pragma unroll
        for (int j = 0; j < 4; ++j) { accm[i][j] = zero; accq[i][j] = zero; }

    for (int kc = 0; kc < 4; ++kc) {
        const ushort* srcA; int strA;
        if (kc < 3) { srcA = Ab + (size_t)node0 * 384 + kc * 128; strA = 384; }
        else        { srcA = xb + (size_t)node0 * 128;            strA = 128; }
        const ushort* srcB = Wb + kc * 128;
        __syncthreads();
        #pragma unroll
        for (int i = 0; i < 8; ++i) {
            int li = i * 256 + tid;            // 0..2047
            int row = li >> 4, cs = li & 15;
            *(uint4*)&lA[row][cs * 8] = *(const uint4*)(srcA + (size_t)row * strA + cs * 8);
            *(uint4*)&lB[row][cs * 8] = *(const uint4*)(srcB + (size_t)row * 512  + cs * 8);
        }
        __syncthreads();
        #pragma unroll
        for (int ks = 0; ks < 4; ++ks) {
            short8 aF[4], bF[4];
            #pragma unroll
            for (int mt = 0; mt < 4; ++mt)
                aF[mt] = *(const short8*)&lA[wm * 64 + mt * 16 + l15][ks * 32 + quad * 8];
            #pragma unroll
            for (int nt = 0; nt < 4; ++nt)
                bF[nt] = *(const short8*)&lB[wn * 64 + nt * 16 + l15][ks * 32 + quad * 8];
            if (kc < 3) {
                #pragma unroll
                for (int mt = 0; mt < 4; ++mt)
                    #pragma unroll
                    for (int nt = 0; nt < 4; ++nt)
                        accm[mt][nt] = __builtin_amdgcn_mfma_f32_16x16x32_bf16(
                            aF[mt], bF[nt], accm[mt][nt], 0, 0, 0);
            } else {
                #pragma unroll
                for (int mt = 0; mt < 4; ++mt)
                    #pragma unroll
                    for (int nt = 0; nt < 4; ++nt)
                        accq[mt][nt] = __builtin_amdgcn_mfma_f32_16x16x32_bf16(
                            aF[mt], bF[nt], accq[mt][nt], 0, 0, 0);
            }
        }
    }

    __syncthreads();   // all fragment reads done; smem becomes v-tile
    #pragma unroll
    for (int mt = 0; mt < 4; ++mt) {
        #pragma unroll
        for (int r = 0; r < 4; ++r) {
            int ml = wm * 64 + mt * 16 + quad * 4 + r;
            float4 c4 = cnts[node0 + ml];
            #pragma unroll
            for (int nt = 0; nt < 4; ++nt) {
                int nl = wn * 64 + nt * 16 + l15;
                float bd = (c4.x * bia[nl] + c4.y * bia[128 + nl] + c4.z * bia[256 + nl]) * c4.w;
                float mval = accm[mt][nt][r] + bd;
                float v = fmaxf(mval, 0.f) + accq[mt][nt][r] + bs[nl];
                vt[ml][nl] = v;
            }
        }
    }
    __syncthreads();
    if (tid < 128) {
        float s1 = 0.f, s2 = 0.f;
        const float* row = vt[tid];
        #pragma unroll 8
        for (int c = 0; c < 128; c += 4) {
            float4 a = *(const float4*)&row[c];
            s1 += (a.x + a.y) + (a.z + a.w);
            s2 += (a.x * a.x + a.y * a.y) + (a.z * a.z + a.w * a.w);
        }
        float mean = s1 * (1.f / 128.f);
        float var = s2 * (1.f / 128.f) - mean * mean;
        sMean[tid] = mean;
        sRstd[tid] = rsqrtf(var + 1e-5f);
    }
    __syncthreads();
    if (OUT_BF16) {
        uint* o = (uint*)out;
        for (int idx = tid; idx < 128 * 64; idx += 256) {
            int row = idx >> 6, cp = idx & 63;
            int node = node0 + row;
            if (node < NNODES) {
                float mn = sMean[row], rs = sRstd[row];
                int c0 = cp * 2;
                float v0 = (vt[row][c0] - mn) * rs * g[c0] + be[c0];
                float v1 = (vt[row][c0 + 1] - mn) * rs * g[c0 + 1] + be[c0 + 1];
                o[(size_t)node * 64 + cp] = pack2(v0, v1);
            }
        }
    } else {
        float* o = (float*)out;
        for (int idx = tid; idx < 128 * 128; idx += 256) {
            int row = idx >> 7, col = idx & 127;
            int node = node0 + row;
            if (node < NNODES)
                o[(size_t)node * 128 + col] =
                    (vt[row][col] - sMean[row]) * sRstd[row] * g[col] + be[col];
        }
    }
}

// ---------------- launch ----------------

extern "C" void kernel_launch(void* const* d_in, const int* in_sizes, int n_in,
                              void* d_out, int out_size, void* d_ws, size_t ws_size,
                              hipStream_t stream) {
    (void)in_sizes; (void)n_in; (void)out_size; (void)ws_size;

    const int*   edges = (const int*)d_in[0];
    const float* xemb  = (const float*)d_in[1];
    const float* W1  = (const float*)d_in[2];
    const float* b1  = (const float*)d_in[3];
    const float* Ws1 = (const float*)d_in[4];
    const float* bs1 = (const float*)d_in[5];
    const float* g1  = (const float*)d_in[6];
    const float* be1 = (const float*)d_in[7];
    const float* W2  = (const float*)d_in[8];
    const float* b2  = (const float*)d_in[9];
    const float* Ws2 = (const float*)d_in[10];
    const float* bs2 = (const float*)d_in[11];
    const float* g2  = (const float*)d_in[12];
    const float* be2 = (const float*)d_in[13];

    char* ws = (char*)d_ws;
    auto take = [&](size_t bytes) {
        char* p = ws;
        ws += (bytes + 255) & ~(size_t)255;
        return p;
    };
    int*    deg3  = (int*)take((size_t)NSEG * 4);
    int*    rs3   = (int*)take((size_t)(NSEG + 1) * 4);
    int*    fill3 = (int*)take((size_t)NSEG * 4);
    int*    part  = (int*)take(512 * 4);
    int*    ppre  = (int*)take(512 * 4);
    int*    elist = (int*)take((size_t)NEDGES * 4);
    float4* cnts  = (float4*)take((size_t)NPAD * 16);
    uint*   xb0   = (uint*)take((size_t)NPAD * 128 * 2);
    uint*   xb1   = (uint*)take((size_t)NPAD * 128 * 2);
    uint*   Ab    = (uint*)take((size_t)NPAD * 384 * 2);
    uint*   Wb1   = (uint*)take((size_t)128 * 512 * 2);
    uint*   Wb2   = (uint*)take((size_t)128 * 512 * 2);

    hipMemsetAsync(deg3, 0, (size_t)NSEG * 4, stream);
    hipMemsetAsync(fill3, 0, (size_t)NSEG * 4, stream);

    deg3_kernel<<<NEDGES / 256, 256, 0, stream>>>(edges, deg3);
    scanA_kernel<<<SCAN_NBLK, 256, 0, stream>>>(deg3, part);
    scanB_kernel<<<1, 512, 0, stream>>>(part, ppre, rs3);
    scanC_kernel<<<SCAN_NBLK, 256, 0, stream>>>(deg3, ppre, rs3);
    cnts_kernel<<<(NNODES + 255) / 256, 256, 0, stream>>>(deg3, cnts);
    fill3_kernel<<<NEDGES / 256, 256, 0, stream>>>(edges, rs3, fill3, elist);

    convx_kernel<<<(NNODES * 64) / 256, 256, 0, stream>>>(xemb, xb0);
    wconv_kernel<<<128, 256, 0, stream>>>(W1, Ws1, Wb1);
    wconv_kernel<<<128, 256, 0, stream>>>(W2, Ws2, Wb2);

    gather_kernel<<<NSEG / 4, 256, 0, stream>>>(
        xb0, rs3, elist, (const float*)cnts, Ab);
    gemm_kernel<true><<<(NNODES + 127) / 128, 256, 0, stream>>>(
        (const ushort*)Ab, (const ushort*)xb0, (const ushort*)Wb1,
        b1, bs1, g1, be1, cnts, xb1);

    gather_kernel<<<NSEG / 4, 256, 0, stream>>>(
        xb1, rs3, elist, (const float*)cnts, Ab);
    gemm_kernel<false><<<(NNODES + 127) / 128, 256, 0, stream>>>(
        (const ushort*)Ab, (const ushort*)xb1, (const ushort*)Wb2,
        b2, bs2, g2, be2, cnts, d_out);
}

// Round 5
// 592.594 us; speedup vs baseline: 2.8473x; 1.1112x over previous
//
#include <hip/hip_runtime.h>
#include <stdint.h>

typedef unsigned int uint;
typedef unsigned short ushort;

#define NNODES 100000
#define NPAD   100096          // NNODES rounded up to 128
#define NEDGES 1600000
#define RCONST 400
#define NSEG   300000
#define SCAN_NBLK 293          // ceil(NSEG/1024)

typedef __attribute__((ext_vector_type(8))) short short8;
typedef __attribute__((ext_vector_type(4))) float f32x4;

__device__ __forceinline__ float bflo(uint u){ union{uint i;float f;}c; c.i=u<<16; return c.f; }
__device__ __forceinline__ float bfhi(uint u){ union{uint i;float f;}c; c.i=u&0xFFFF0000u; return c.f; }
__device__ __forceinline__ ushort f2bf(float f){ union{uint i;float ff;}c; c.ff=f; uint u=c.i;
    return (ushort)((u + 0x7FFFu + ((u>>16)&1u))>>16); }
__device__ __forceinline__ uint pack2(float lo, float hi){
    return (uint)f2bf(lo) | ((uint)f2bf(hi)<<16); }

// ---------------- CSR build ----------------

__global__ __launch_bounds__(256) void deg3_kernel(const int* __restrict__ edges,
                                                   int* __restrict__ deg3) {
    int e = blockIdx.x * 256 + threadIdx.x;
    if (e < NEDGES) {
        int rel = edges[e * 3 + 1];
        int dst = edges[e * 3 + 2];
        int bkt = (rel >= RCONST) + (rel >= 2 * RCONST);
        atomicAdd(&deg3[dst * 3 + bkt], 1);
    }
}

__global__ __launch_bounds__(256) void scanA_kernel(const int* __restrict__ deg,
                                                    int* __restrict__ part) {
    __shared__ int sm[256];
    int t = threadIdx.x, b = blockIdx.x;
    int base = b * 1024 + t * 4;
    int s = 0;
    #pragma unroll
    for (int j = 0; j < 4; ++j) { int i = base + j; if (i < NSEG) s += deg[i]; }
    sm[t] = s; __syncthreads();
    for (int st = 1; st < 256; st <<= 1) {
        int a = (t >= st) ? sm[t - st] : 0;
        __syncthreads(); sm[t] += a; __syncthreads();
    }
    if (t == 255) part[b] = sm[255];
}

__global__ __launch_bounds__(512) void scanB_kernel(const int* __restrict__ part,
                                                    int* __restrict__ ppre,
                                                    int* __restrict__ rs3) {
    __shared__ int sm[512];
    int t = threadIdx.x;
    int v = (t < SCAN_NBLK) ? part[t] : 0;
    sm[t] = v; __syncthreads();
    for (int st = 1; st < 512; st <<= 1) {
        int a = (t >= st) ? sm[t - st] : 0;
        __syncthreads(); sm[t] += a; __syncthreads();
    }
    if (t < SCAN_NBLK) ppre[t] = sm[t] - v;
    if (t == 511) rs3[NSEG] = sm[511];
}

__global__ __launch_bounds__(256) void scanC_kernel(const int* __restrict__ deg,
                                                    const int* __restrict__ ppre,
                                                    int* __restrict__ rs3,
                                                    int* __restrict__ rsCtr) {
    __shared__ int sm[256];
    int t = threadIdx.x, b = blockIdx.x;
    int base = b * 1024 + t * 4;
    int d0 = 0, d1 = 0, d2 = 0, d3 = 0;
    if (base + 3 < NSEG) {
        int4 q = *(const int4*)&deg[base];
        d0 = q.x; d1 = q.y; d2 = q.z; d3 = q.w;
    } else {
        if (base < NSEG)     d0 = deg[base];
        if (base + 1 < NSEG) d1 = deg[base + 1];
        if (base + 2 < NSEG) d2 = deg[base + 2];
        if (base + 3 < NSEG) d3 = deg[base + 3];
    }
    int tot = d0 + d1 + d2 + d3;
    sm[t] = tot; __syncthreads();
    for (int st = 1; st < 256; st <<= 1) {
        int a = (t >= st) ? sm[t - st] : 0;
        __syncthreads(); sm[t] += a; __syncthreads();
    }
    int run = ppre[b] + sm[t] - tot;
    if (base < NSEG)     { rs3[base]     = run; rsCtr[base]     = run; run += d0; }
    if (base + 1 < NSEG) { rs3[base + 1] = run; rsCtr[base + 1] = run; run += d1; }
    if (base + 2 < NSEG) { rs3[base + 2] = run; rsCtr[base + 2] = run; run += d2; }
    if (base + 3 < NSEG) { rs3[base + 3] = run; rsCtr[base + 3] = run; }
}

// per-node meta: aligned boundary quad + float counts for the gemm epilogue
__global__ __launch_bounds__(256) void meta_kernel(const int* __restrict__ rs3,
                                                   int4* __restrict__ rs4,
                                                   float4* __restrict__ cnts) {
    int n = blockIdx.x * 256 + threadIdx.x;
    if (n < NNODES) {
        int b0 = rs3[n * 3], b1 = rs3[n * 3 + 1], b2 = rs3[n * 3 + 2], b3 = rs3[n * 3 + 3];
        int4 q; q.x = b0; q.y = b1; q.z = b2; q.w = b3;
        rs4[n] = q;
        float c0 = (float)(b1 - b0), c1 = (float)(b2 - b1), c2 = (float)(b3 - b2);
        float4 v; v.x = c0; v.y = c1; v.z = c2; v.w = 1.0f / fmaxf(c0 + c1 + c2, 1.0f);
        cnts[n] = v;
    }
}

__global__ __launch_bounds__(256) void fill3_kernel(const int* __restrict__ edges,
                                                    int* __restrict__ rsCtr,
                                                    int* __restrict__ elist) {
    int e = blockIdx.x * 256 + threadIdx.x;
    if (e < NEDGES) {
        int src = edges[e * 3];
        int rel = edges[e * 3 + 1];
        int dst = edges[e * 3 + 2];
        int bkt = (rel >= RCONST) + (rel >= 2 * RCONST);
        int pos = atomicAdd(&rsCtr[dst * 3 + bkt], 1);
        elist[pos] = src;
    }
}

// ---------------- conversions ----------------

__global__ __launch_bounds__(256) void convx_kernel(const float* __restrict__ x,
                                                    uint* __restrict__ xb) {
    size_t i = (size_t)blockIdx.x * 256 + threadIdx.x;   // pair index
    if (i < (size_t)NNODES * 64) {
        float2 f = *(const float2*)&x[i * 2];
        xb[i] = pack2(f.x, f.y);
    }
}

// Wb[n][k] bf16, k<384: W[k>>7][n][k&127]; k>=384: Ws[n][k-384]
__global__ __launch_bounds__(256) void wconv_kernel(const float* __restrict__ W,
                                                    const float* __restrict__ Ws,
                                                    uint* __restrict__ Wb) {
    int i = blockIdx.x * 256 + threadIdx.x;   // pair index, 128*256
    if (i < 128 * 256) {
        int n = i >> 8, kp = i & 255, k = kp * 2;
        float v0, v1;
        if (k < 384) {
            int r = k >> 7, kk = k & 127;
            const float* p = W + r * 16384 + n * 128 + kk;
            v0 = p[0]; v1 = p[1];
        } else {
            const float* p = Ws + n * 128 + (k - 384);
            v0 = p[0]; v1 = p[1];
        }
        Wb[i] = pack2(v0, v1);
    }
}

// ---------------- gather: one wave per node, flat one-hot edge loop ----------
// A[node][r*128..+128] = inv * sum_{e in bucket r} x[src_e]   (bf16)
// Edge indices pulled to SGPR via readlane; bucket masks are wave-uniform.

__global__ __launch_bounds__(256) void gather_kernel(
    const uint* __restrict__ xb,       // [NPAD][64] bf16-pairs
    const int4* __restrict__ rs4,      // per-node (b0,b1,b2,b3)
    const int* __restrict__ elist,
    uint* __restrict__ Ab) {           // [NPAD][192] bf16-pairs
    int w = threadIdx.x >> 6, lane = threadIdx.x & 63;
    int node = blockIdx.x * 4 + w;     // grid = NNODES/4 exactly
    int4 bq = rs4[node];
    int b0 = bq.x, b1 = bq.y, b2 = bq.z, b3 = bq.w;
    float inv = 1.0f / fmaxf((float)(b3 - b0), 1.0f);

    float a0l = 0.f, a0h = 0.f, a1l = 0.f, a1h = 0.f, a2l = 0.f, a2h = 0.f;

    for (int base = b0; base < b3; base += 64) {
        int m = min(64, b3 - base);
        int ve = 0;
        if (lane < m) ve = elist[base + lane];

        int j = 0;
        for (; j + 4 <= m; j += 4) {
            int t0 = base + j;
            int s0 = __builtin_amdgcn_readlane(ve, j);
            int s1 = __builtin_amdgcn_readlane(ve, j + 1);
            int s2 = __builtin_amdgcn_readlane(ve, j + 2);
            int s3 = __builtin_amdgcn_readlane(ve, j + 3);
            uint u0 = xb[((size_t)s0 << 6) + lane];
            uint u1 = xb[((size_t)s1 << 6) + lane];
            uint u2 = xb[((size_t)s2 << 6) + lane];
            uint u3 = xb[((size_t)s3 << 6) + lane];

            float q00 = (t0     < b1) ? 1.f : 0.f, q01 = ((t0     >= b1) & (t0     < b2)) ? 1.f : 0.f, q02 = (t0     >= b2) ? 1.f : 0.f;
            float q10 = (t0 + 1 < b1) ? 1.f : 0.f, q11 = ((t0 + 1 >= b1) & (t0 + 1 < b2)) ? 1.f : 0.f, q12 = (t0 + 1 >= b2) ? 1.f : 0.f;
            float q20 = (t0 + 2 < b1) ? 1.f : 0.f, q21 = ((t0 + 2 >= b1) & (t0 + 2 < b2)) ? 1.f : 0.f, q22 = (t0 + 2 >= b2) ? 1.f : 0.f;
            float q30 = (t0 + 3 < b1) ? 1.f : 0.f, q31 = ((t0 + 3 >= b1) & (t0 + 3 < b2)) ? 1.f : 0.f, q32 = (t0 + 3 >= b2) ? 1.f : 0.f;

            float f0l = bflo(u0), f0h = bfhi(u0);
            float f1l = bflo(u1), f1h = bfhi(u1);
            float f2l = bflo(u2), f2h = bfhi(u2);
            float f3l = bflo(u3), f3h = bfhi(u3);

            a0l = fmaf(q00, f0l, a0l); a1l = fmaf(q01, f0l, a1l); a2l = fmaf(q02, f0l, a2l);
            a0h = fmaf(q00, f0h, a0h); a1h = fmaf(q01, f0h, a1h); a2h = fmaf(q02, f0h, a2h);
            a0l = fmaf(q10, f1l, a0l); a1l = fmaf(q11, f1l, a1l); a2l = fmaf(q12, f1l, a2l);
            a0h = fmaf(q10, f1h, a0h); a1h = fmaf(q11, f1h, a1h); a2h = fmaf(q12, f1h, a2h);
            a0l = fmaf(q20, f2l, a0l); a1l = fmaf(q21, f2l, a1l); a2l = fmaf(q22, f2l, a2l);
            a0h = fmaf(q20, f2h, a0h); a1h = fmaf(q21, f2h, a1h); a2h = fmaf(q22, f2h, a2h);
            a0l = fmaf(q30, f3l, a0l); a1l = fmaf(q31, f3l, a1l); a2l = fmaf(q32, f3l, a2l);
            a0h = fmaf(q30, f3h, a0h); a1h = fmaf(q31, f3h, a1h); a2h = fmaf(q32, f3h, a2h);
        }
        for (; j < m; ++j) {
            int t = base + j;
            int s = __builtin_amdgcn_readlane(ve, j);
            uint u = xb[((size_t)s << 6) + lane];
            float q0 = (t < b1) ? 1.f : 0.f;
            float q1 = ((t >= b1) & (t < b2)) ? 1.f : 0.f;
            float q2 = (t >= b2) ? 1.f : 0.f;
            float fl = bflo(u), fh = bfhi(u);
            a0l = fmaf(q0, fl, a0l); a1l = fmaf(q1, fl, a1l); a2l = fmaf(q2, fl, a2l);
            a0h = fmaf(q0, fh, a0h); a1h = fmaf(q1, fh, a1h); a2h = fmaf(q2, fh, a2h);
        }
    }

    size_t ab = (size_t)node * 192 + lane;
    Ab[ab]       = pack2(a0l * inv, a0h * inv);
    Ab[ab + 64]  = pack2(a1l * inv, a1h * inv);
    Ab[ab + 128] = pack2(a2l * inv, a2h * inv);
}

// ---------------- MFMA GEMM + fused epilogue ----------------

template<bool OUT_BF16>
__global__ __launch_bounds__(256, 2) void gemm_kernel(
    const ushort* __restrict__ Ab,     // [NPAD][384]
    const ushort* __restrict__ xb,     // [NPAD][128]
    const ushort* __restrict__ Wb,     // [128][512]
    const float* __restrict__ bia,     // [3][128]
    const float* __restrict__ bs,
    const float* __restrict__ g,
    const float* __restrict__ be,
    const float4* __restrict__ cnts,   // [NPAD] (c0,c1,c2,inv)
    void* __restrict__ out) {
    __shared__ char smem[128 * 136 * 2 * 2];   // A-stage + B-stage, reused as v-tile
    __shared__ float sMean[128], sRstd[128];
    ushort (*lA)[136] = (ushort(*)[136])smem;
    ushort (*lB)[136] = (ushort(*)[136])(smem + 128 * 136 * 2);
    float  (*vt)[132] = (float(*)[132])smem;

    int tid = threadIdx.x;
    int w = tid >> 6, lane = tid & 63;
    int wm = w >> 1, wn = w & 1;
    int quad = lane >> 4, l15 = lane & 15;
    int node0 = blockIdx.x * 128;

    f32x4 accm[4][4], accq[4][4];
    f32x4 zero = {0.f, 0.f, 0.f, 0.f};
    #pragma unroll
    for (int i = 0; i < 4; ++i)
        #pragma unroll
        for (int j = 0; j < 4; ++j) { accm[i][j] = zero; accq[i][j] = zero; }

    for (int kc = 0; kc < 4; ++kc) {
        const ushort* srcA; int strA;
        if (kc < 3) { srcA = Ab + (size_t)node0 * 384 + kc * 128; strA = 384; }
        else        { srcA = xb + (size_t)node0 * 128;            strA = 128; }
        const ushort* srcB = Wb + kc * 128;
        __syncthreads();
        #pragma unroll
        for (int i = 0; i < 8; ++i) {
            int li = i * 256 + tid;            // 0..2047
            int row = li >> 4, cs = li & 15;
            *(uint4*)&lA[row][cs * 8] = *(const uint4*)(srcA + (size_t)row * strA + cs * 8);
            *(uint4*)&lB[row][cs * 8] = *(const uint4*)(srcB + (size_t)row * 512  + cs * 8);
        }
        __syncthreads();
        #pragma unroll
        for (int ks = 0; ks < 4; ++ks) {
            short8 aF[4], bF[4];
            #pragma unroll
            for (int mt = 0; mt < 4; ++mt)
                aF[mt] = *(const short8*)&lA[wm * 64 + mt * 16 + l15][ks * 32 + quad * 8];
            #pragma unroll
            for (int nt = 0; nt < 4; ++nt)
                bF[nt] = *(const short8*)&lB[wn * 64 + nt * 16 + l15][ks * 32 + quad * 8];
            if (kc < 3) {
                #pragma unroll
                for (int mt = 0; mt < 4; ++mt)
                    #pragma unroll
                    for (int nt = 0; nt < 4; ++nt)
                        accm[mt][nt] = __builtin_amdgcn_mfma_f32_16x16x32_bf16(
                            aF[mt], bF[nt], accm[mt][nt], 0, 0, 0);
            } else {
                #pragma unroll
                for (int mt = 0; mt < 4; ++mt)
                    #pragma unroll
                    for (int nt = 0; nt < 4; ++nt)
                        accq[mt][nt] = __builtin_amdgcn_mfma_f32_16x16x32_bf16(
                            aF[mt], bF[nt], accq[mt][nt], 0, 0, 0);
            }
        }
    }

    __syncthreads();   // all fragment reads done; smem becomes v-tile
    #pragma unroll
    for (int mt = 0; mt < 4; ++mt) {
        #pragma unroll
        for (int r = 0; r < 4; ++r) {
            int ml = wm * 64 + mt * 16 + quad * 4 + r;
            float4 c4 = cnts[node0 + ml];
            #pragma unroll
            for (int nt = 0; nt < 4; ++nt) {
                int nl = wn * 64 + nt * 16 + l15;
                float bd = (c4.x * bia[nl] + c4.y * bia[128 + nl] + c4.z * bia[256 + nl]) * c4.w;
                float mval = accm[mt][nt][r] + bd;
                float v = fmaxf(mval, 0.f) + accq[mt][nt][r] + bs[nl];
                vt[ml][nl] = v;
            }
        }
    }
    __syncthreads();
    if (tid < 128) {
        float s1 = 0.f, s2 = 0.f;
        const float* row = vt[tid];
        #pragma unroll 8
        for (int c = 0; c < 128; c += 4) {
            float4 a = *(const float4*)&row[c];
            s1 += (a.x + a.y) + (a.z + a.w);
            s2 += (a.x * a.x + a.y * a.y) + (a.z * a.z + a.w * a.w);
        }
        float mean = s1 * (1.f / 128.f);
        float var = s2 * (1.f / 128.f) - mean * mean;
        sMean[tid] = mean;
        sRstd[tid] = rsqrtf(var + 1e-5f);
    }
    __syncthreads();
    if (OUT_BF16) {
        uint* o = (uint*)out;
        for (int idx = tid; idx < 128 * 64; idx += 256) {
            int row = idx >> 6, cp = idx & 63;
            int node = node0 + row;
            if (node < NNODES) {
                float mn = sMean[row], rs = sRstd[row];
                int c0 = cp * 2;
                float v0 = (vt[row][c0] - mn) * rs * g[c0] + be[c0];
                float v1 = (vt[row][c0 + 1] - mn) * rs * g[c0 + 1] + be[c0 + 1];
                o[(size_t)node * 64 + cp] = pack2(v0, v1);
            }
        }
    } else {
        float* o = (float*)out;
        for (int idx = tid; idx < 128 * 128; idx += 256) {
            int row = idx >> 7, col = idx & 127;
            int node = node0 + row;
            if (node < NNODES)
                o[(size_t)node * 128 + col] =
                    (vt[row][col] - sMean[row]) * sRstd[row] * g[col] + be[col];
        }
    }
}

// ---------------- launch ----------------

extern "C" void kernel_launch(void* const* d_in, const int* in_sizes, int n_in,
                              void* d_out, int out_size, void* d_ws, size_t ws_size,
                              hipStream_t stream) {
    (void)in_sizes; (void)n_in; (void)out_size; (void)ws_size;

    const int*   edges = (const int*)d_in[0];
    const float* xemb  = (const float*)d_in[1];
    const float* W1  = (const float*)d_in[2];
    const float* b1  = (const float*)d_in[3];
    const float* Ws1 = (const float*)d_in[4];
    const float* bs1 = (const float*)d_in[5];
    const float* g1  = (const float*)d_in[6];
    const float* be1 = (const float*)d_in[7];
    const float* W2  = (const float*)d_in[8];
    const float* b2  = (const float*)d_in[9];
    const float* Ws2 = (const float*)d_in[10];
    const float* bs2 = (const float*)d_in[11];
    const float* g2  = (const float*)d_in[12];
    const float* be2 = (const float*)d_in[13];

    char* ws = (char*)d_ws;
    auto take = [&](size_t bytes) {
        char* p = ws;
        ws += (bytes + 255) & ~(size_t)255;
        return p;
    };
    int*    deg3  = (int*)take((size_t)NSEG * 4);
    int*    rs3   = (int*)take((size_t)(NSEG + 1) * 4);
    int*    rsCtr = (int*)take((size_t)(NSEG + 1) * 4);
    int*    part  = (int*)take(512 * 4);
    int*    ppre  = (int*)take(512 * 4);
    int*    elist = (int*)take((size_t)NEDGES * 4);
    int4*   rs4   = (int4*)take((size_t)NPAD * 16);
    float4* cnts  = (float4*)take((size_t)NPAD * 16);
    uint*   xb0   = (uint*)take((size_t)NPAD * 128 * 2);
    uint*   xb1   = (uint*)take((size_t)NPAD * 128 * 2);
    uint*   Ab    = (uint*)take((size_t)NPAD * 384 * 2);
    uint*   Wb1   = (uint*)take((size_t)128 * 512 * 2);
    uint*   Wb2   = (uint*)take((size_t)128 * 512 * 2);

    hipMemsetAsync(deg3, 0, (size_t)NSEG * 4, stream);

    deg3_kernel<<<NEDGES / 256, 256, 0, stream>>>(edges, deg3);
    scanA_kernel<<<SCAN_NBLK, 256, 0, stream>>>(deg3, part);
    scanB_kernel<<<1, 512, 0, stream>>>(part, ppre, rs3);
    scanC_kernel<<<SCAN_NBLK, 256, 0, stream>>>(deg3, ppre, rs3, rsCtr);
    meta_kernel<<<(NNODES + 255) / 256, 256, 0, stream>>>(rs3, rs4, cnts);
    fill3_kernel<<<NEDGES / 256, 256, 0, stream>>>(edges, rsCtr, elist);

    convx_kernel<<<(NNODES * 64) / 256, 256, 0, stream>>>(xemb, xb0);
    wconv_kernel<<<128, 256, 0, stream>>>(W1, Ws1, Wb1);
    wconv_kernel<<<128, 256, 0, stream>>>(W2, Ws2, Wb2);

    gather_kernel<<<NNODES / 4, 256, 0, stream>>>(xb0, rs4, elist, Ab);
    gemm_kernel<true><<<(NNODES + 127) / 128, 256, 0, stream>>>(
        (const ushort*)Ab, (const ushort*)xb0, (const ushort*)Wb1,
        b1, bs1, g1, be1, cnts, xb1);

    gather_kernel<<<NNODES / 4, 256, 0, stream>>>(xb1, rs4, elist, Ab);
    gemm_kernel<false><<<(NNODES + 127) / 128, 256, 0, stream>>>(
        (const ushort*)Ab, (const ushort*)xb1, (const ushort*)Wb2,
        b2, bs2, g2, be2, cnts, d_out);
}